// Round 1
// baseline (163.575 us; speedup 1.0000x reference)
//
#include <hip/hip_runtime.h>

// CollisionLoss: loss = sum_{b,t,n} relu(tx[b,n] - |ex[b,t]-cx[b,n]|)
//                              * relu(ty[b,n] - |ey[b,t]-cy[b,n]|) * valid
//                / max(sum(ego_mask>=1), 1)
// Shapes: pred_abs (B,T,2) f32, gt_bboxes (B,N,9) f32,
//         gt_ego_fut_masks (B,T) i32, agent_mask (B,N) i32. B=4096,T=12,N=512.

#define T_DIM 12
#define N_DIM 512

__global__ __launch_bounds__(256) void collision_loss_main(
    const float* __restrict__ pred_abs,   // (B,T,2)
    const float* __restrict__ gt_bboxes,  // (B,N,9)
    const int*   __restrict__ ego_masks,  // (B,T)
    const int*   __restrict__ agent_mask, // (B,N)
    float* __restrict__ loss_acc,         // ws float slot
    int*   __restrict__ count_acc)        // ws int slot
{
    __shared__ float s_ex[T_DIM];
    __shared__ float s_ey[T_DIM];
    __shared__ float s_part[4];

    const int bid   = blockIdx.x;
    const int b     = bid >> 1;      // batch index
    const int nhalf = bid & 1;       // which half of the 512 agents
    const int tid   = threadIdx.x;

    // Stage ego trajectory for this batch; fold invalid ego -> ex=+1e30 so
    // tx - |ex - cx| is hugely negative -> relu gives 0 (branch-free).
    int ev = 0;
    if (tid < T_DIM) {
        ev = (ego_masks[b * T_DIM + tid] >= 1) ? 1 : 0;
        const float ex = pred_abs[(b * T_DIM + tid) * 2 + 0];
        const float ey = pred_abs[(b * T_DIM + tid) * 2 + 1];
        s_ex[tid] = ev ? ex : 1e30f;
        s_ey[tid] = ev ? ey : 1e30f;
    }

    // n_valid contribution: count valid ego steps once per batch (nhalf==0).
    if (nhalf == 0) {
        unsigned long long m = __ballot(ev != 0);  // wave0 lanes 0..11 carry ev
        if (tid == 0 && m) atomicAdd(count_acc, __popcll(m));
    }
    __syncthreads();

    // Each thread owns one agent n.
    const int n = (nhalf << 8) + tid;
    const size_t rowoff = ((size_t)b * N_DIM + n) * 9;
    const float cx = gt_bboxes[rowoff + 0];
    const float cy = gt_bboxes[rowoff + 1];
    const float ax = gt_bboxes[rowoff + 3];
    const float ay = gt_bboxes[rowoff + 4];
    const int   av = agent_mask[b * N_DIM + n] >= 1;

    // Fold invalid agent -> tx = -1e30 so relu gives 0 (branch-free).
    const float tx = av ? ((1.85f + 0.5f) * 0.5f + ax * 0.5f + 1.5f) : -1e30f;
    const float ty = (4.084f + 0.5f) * 0.5f + ay * 0.5f + 1.5f;

    float acc = 0.0f;
    #pragma unroll
    for (int t = 0; t < T_DIM; ++t) {
        const float px = fmaxf(tx - fabsf(s_ex[t] - cx), 0.0f);
        const float py = fmaxf(ty - fabsf(s_ey[t] - cy), 0.0f);
        acc += px * py;
    }

    // Block reduction: wave shuffle, then LDS across the 4 waves.
    #pragma unroll
    for (int off = 32; off > 0; off >>= 1) acc += __shfl_down(acc, off);
    const int wave = tid >> 6;
    if ((tid & 63) == 0) s_part[wave] = acc;
    __syncthreads();
    if (tid == 0) {
        const float s = s_part[0] + s_part[1] + s_part[2] + s_part[3];
        atomicAdd(loss_acc, s);
    }
}

__global__ void collision_loss_finalize(const float* __restrict__ loss_acc,
                                        const int*   __restrict__ count_acc,
                                        float* __restrict__ out)
{
    out[0] = loss_acc[0] / fmaxf((float)count_acc[0], 1.0f);
}

extern "C" void kernel_launch(void* const* d_in, const int* in_sizes, int n_in,
                              void* d_out, int out_size, void* d_ws, size_t ws_size,
                              hipStream_t stream)
{
    const float* pred_abs   = (const float*)d_in[0];
    const float* gt_bboxes  = (const float*)d_in[1];
    const int*   ego_masks  = (const int*)d_in[2];
    const int*   agent_mask = (const int*)d_in[3];
    float* out = (float*)d_out;

    const int B = in_sizes[0] / (T_DIM * 2);  // 4096

    float* loss_acc = (float*)d_ws;
    int*   count_acc = (int*)d_ws + 1;

    // Zero the two accumulator slots each call (graph-capture safe).
    hipMemsetAsync(d_ws, 0, 2 * sizeof(float), stream);

    dim3 grid(B * 2);  // (b, n-half) -> 8192 blocks of 256 threads
    collision_loss_main<<<grid, 256, 0, stream>>>(
        pred_abs, gt_bboxes, ego_masks, agent_mask, loss_acc, count_acc);

    collision_loss_finalize<<<1, 1, 0, stream>>>(loss_acc, count_acc, out);
}

// Round 2
// 21.554 us; speedup vs baseline: 7.5892x; 7.5892x over previous
//
#include <hip/hip_runtime.h>

// CollisionLoss: loss = sum_{b,t,n} relu(tx[b,n] - |ex[b,t]-cx[b,n]|)
//                              * relu(ty[b,n] - |ey[b,t]-cy[b,n]|) * valid
//                / max(sum(ego_mask>=1), 1)
// Shapes: pred_abs (B,T,2) f32, gt_bboxes (B,N,9) f32,
//         gt_ego_fut_masks (B,T) i32, agent_mask (B,N) i32. B=4096,T=12,N=512.
//
// R1 lesson: 12k same-address device atomics serialized the whole dispatch
// (153us with VALUBusy 4.6%, ~0 HBM). Now: per-block plain stores to ws,
// separate tree-reduce kernel. Zero atomics.

#define T_DIM 12
#define N_DIM 512

__global__ __launch_bounds__(256) void collision_loss_main(
    const float* __restrict__ pred_abs,   // (B,T,2)
    const float* __restrict__ gt_bboxes,  // (B,N,9)
    const int*   __restrict__ ego_masks,  // (B,T)
    const int*   __restrict__ agent_mask, // (B,N)
    float* __restrict__ ws_loss,          // (B) per-block partial loss
    int*   __restrict__ ws_cnt)           // (B) per-block ego-valid count
{
    __shared__ float s_ex[T_DIM];
    __shared__ float s_ey[T_DIM];
    __shared__ float s_part[4];

    const int b   = blockIdx.x;   // one block per batch element
    const int tid = threadIdx.x;

    // Stage ego trajectory; fold invalid ego -> ex=+1e30 so relu gives 0.
    int ev = 0;
    if (tid < T_DIM) {
        ev = (ego_masks[b * T_DIM + tid] >= 1) ? 1 : 0;
        const float ex = pred_abs[(b * T_DIM + tid) * 2 + 0];
        const float ey = pred_abs[(b * T_DIM + tid) * 2 + 1];
        s_ex[tid] = ev ? ex : 1e30f;
        s_ey[tid] = ev ? ey : 1e30f;
    }
    // Wave 0 lanes 0..11 carry ev; ballot is wave-wide (all lanes exec).
    unsigned long long m = __ballot(ev != 0);
    if (tid == 0) ws_cnt[b] = __popcll(m);
    __syncthreads();

    // Each thread owns agents n0 = tid and n1 = tid + 256.
    const int n0 = tid;
    const int n1 = tid + 256;
    const size_t r0 = ((size_t)b * N_DIM + n0) * 9;
    const size_t r1 = ((size_t)b * N_DIM + n1) * 9;

    const float cx0 = gt_bboxes[r0 + 0], cy0 = gt_bboxes[r0 + 1];
    const float ax0 = gt_bboxes[r0 + 3], ay0 = gt_bboxes[r0 + 4];
    const float cx1 = gt_bboxes[r1 + 0], cy1 = gt_bboxes[r1 + 1];
    const float ax1 = gt_bboxes[r1 + 3], ay1 = gt_bboxes[r1 + 4];
    const int av0 = agent_mask[b * N_DIM + n0] >= 1;
    const int av1 = agent_mask[b * N_DIM + n1] >= 1;

    // Invalid agent -> tx = -1e30 so relu gives 0 (branch-free inner loop).
    const float tx0 = av0 ? ((1.85f + 0.5f) * 0.5f + ax0 * 0.5f + 1.5f) : -1e30f;
    const float tx1 = av1 ? ((1.85f + 0.5f) * 0.5f + ax1 * 0.5f + 1.5f) : -1e30f;
    const float ty0 = (4.084f + 0.5f) * 0.5f + ay0 * 0.5f + 1.5f;
    const float ty1 = (4.084f + 0.5f) * 0.5f + ay1 * 0.5f + 1.5f;

    float acc = 0.0f;
    #pragma unroll
    for (int t = 0; t < T_DIM; ++t) {
        const float ex = s_ex[t], ey = s_ey[t];
        const float px0 = fmaxf(tx0 - fabsf(ex - cx0), 0.0f);
        const float py0 = fmaxf(ty0 - fabsf(ey - cy0), 0.0f);
        const float px1 = fmaxf(tx1 - fabsf(ex - cx1), 0.0f);
        const float py1 = fmaxf(ty1 - fabsf(ey - cy1), 0.0f);
        acc += px0 * py0 + px1 * py1;
    }

    // Block reduction: wave shuffle, then LDS across the 4 waves.
    #pragma unroll
    for (int off = 32; off > 0; off >>= 1) acc += __shfl_down(acc, off);
    const int wave = tid >> 6;
    if ((tid & 63) == 0) s_part[wave] = acc;
    __syncthreads();
    if (tid == 0)
        ws_loss[b] = s_part[0] + s_part[1] + s_part[2] + s_part[3];
}

// Single-block reduce of the 4096 partials -> out[0].
__global__ __launch_bounds__(1024) void collision_loss_reduce(
    const float* __restrict__ ws_loss,
    const int*   __restrict__ ws_cnt,
    float* __restrict__ out, int nB)
{
    __shared__ float s_l[16];
    __shared__ float s_c[16];
    const int tid = threadIdx.x;

    float l = 0.0f;
    float c = 0.0f;
    for (int i = tid; i < nB; i += 1024) {
        l += ws_loss[i];
        c += (float)ws_cnt[i];
    }
    #pragma unroll
    for (int off = 32; off > 0; off >>= 1) {
        l += __shfl_down(l, off);
        c += __shfl_down(c, off);
    }
    const int wave = tid >> 6;
    if ((tid & 63) == 0) { s_l[wave] = l; s_c[wave] = c; }
    __syncthreads();
    if (tid == 0) {
        float L = 0.0f, C = 0.0f;
        #pragma unroll
        for (int w = 0; w < 16; ++w) { L += s_l[w]; C += s_c[w]; }
        out[0] = L / fmaxf(C, 1.0f);
    }
}

extern "C" void kernel_launch(void* const* d_in, const int* in_sizes, int n_in,
                              void* d_out, int out_size, void* d_ws, size_t ws_size,
                              hipStream_t stream)
{
    const float* pred_abs   = (const float*)d_in[0];
    const float* gt_bboxes  = (const float*)d_in[1];
    const int*   ego_masks  = (const int*)d_in[2];
    const int*   agent_mask = (const int*)d_in[3];
    float* out = (float*)d_out;

    const int B = in_sizes[0] / (T_DIM * 2);  // 4096

    float* ws_loss = (float*)d_ws;
    int*   ws_cnt  = (int*)d_ws + B;

    collision_loss_main<<<dim3(B), 256, 0, stream>>>(
        pred_abs, gt_bboxes, ego_masks, agent_mask, ws_loss, ws_cnt);

    collision_loss_reduce<<<dim3(1), 1024, 0, stream>>>(ws_loss, ws_cnt, out, B);
}